// Round 8
// baseline (36725.876 us; speedup 1.0000x reference)
//
#include <hip/hip_runtime.h>

#define NHID 512
#define NXW  128
#define TLEN 16384
#define STEPS (TLEN - NXW)      // 16256
#define G    32                 // persistent workgroups
#define B    512                // 8 waves per WG
#define RPW  16                 // hidden rows owned per WG
#define RSLOTS 8                // sync ring depth (32 KB -> stays IC/L2-hot)
#define PSTRIDE 65              // padded partials stride (<=2-way bank aliasing)

#define FOR4(M)  M(0) M(1) M(2) M(3)
#define FOR16(M) M(0) M(1) M(2) M(3) M(4) M(5) M(6) M(7) \
                 M(8) M(9) M(10) M(11) M(12) M(13) M(14) M(15)

__device__ __forceinline__ float sigmoid_f(float v) { return 1.f / (1.f + __expf(-v)); }
__device__ __forceinline__ float tanh_f(float v)    { return 1.f - 2.f / (1.f + __expf(2.f * v)); }

#define AL(p) __hip_atomic_load((p), __ATOMIC_RELAXED, __HIP_MEMORY_SCOPE_AGENT)
#define ASTR(p, v) __hip_atomic_store((p), (v), __ATOMIC_RELAXED, __HIP_MEMORY_SCOPE_AGENT)

// ---------------------------------------------------------------------------
// R8 = R0 skeleton (verified 25.6 ms) with the wave0-only tail DISTRIBUTED
// across all 8 waves. Poll side is R0-verbatim (R4's lesson: don't touch it).
//
// MAIN mapping (poll + x-proj + U.h dot, unchanged from R0):
//   wave w = k-slice [w*64, w*64+64); lane l = output (gate q=l>>4,
//   row rowM = g*16 + (l&15)). Wave w polls ring words [w*64+l].
//
// TAIL mapping (after the one barrier, NEW):
//   wave w owns rows {g*16+2w, g*16+2w+1} end-to-end.
//   lane l -> s = l&7 (k-slice), oi = l>>3, tq = oi>>1 (gate), rh = oi&1.
//   Lane reads ONE partial p[s*65 + tq*16 + 2w + rh] (banks (s + o) % 32:
//   <=2-way = free), 3-hop shfl_xor over s gives the full 8-slice sum,
//   activate (tq<3: sigmoid, else tanh), 4-shfl gate gather (bl = l&15),
//   all lanes track c redundantly, lanes {0,8} publish rows 2w,2w+1.
//   vs R0: no 7-LDS-read serial reduce in one wave, no 16-store batch from
//   one lane group, publishes issued from 8 waves concurrently ~200 cy
//   earlier, 0/8 waves idle during the tail.
//
// Ring word = {tag:32 | h_bits:32}; consumer of step t polls slot (t-1)&7
// until tag == t-1. Harness 0xAA poison = tag 0xAAAAAAAA, never a valid t.
// Slot reuse race-free: observing tag t-1 on all words means every wave
// published t-1, which required passing its WG barrier at t-1, which
// required validating tags t-2 -> transitively no wave still reads tags
// <= t-2; overwriting slot t&7 (tag t-8) is safe with depth 8.
//
// partials double-buffer with ONE barrier is safe by the same ring-depth
// argument: a wave writing partials[(t+2)&1] validated tags t+1, which
// proves every wave finished its step-t tail reads of partials[t&1].
// h_hist gets plain stores purely for the mu epilogue.
// ---------------------------------------------------------------------------
__launch_bounds__(B, 2)
__global__ void lstm_persistent(
    const float* x,
    const float* Wf, const float* Uf, const float* bf,
    const float* Wi, const float* Ui, const float* bi,
    const float* Wo, const float* Uo, const float* bo,
    const float* Wc, const float* Uc, const float* bc,
    unsigned long long* ring,     // [RSLOTS][NHID] packed {tag,h}
    float* h_hist)                // [STEPS][NHID] for mu only
{
    __shared__ float x_win[256];                    // x ring: refill every 128 steps
    __shared__ __align__(16) float h_buf[8][64];    // per-wave h-slice staging
    __shared__ float partials[2][8 * PSTRIDE];      // double-buffered, padded

    const int tid = threadIdx.x;
    const int g   = blockIdx.x;
    const int w   = tid >> 6;            // wave
    const int l   = tid & 63;

    // MAIN mapping (weights / dot / poll)
    const int q    = l >> 4;             // gate 0=f 1=i 2=o 3=c
    const int rowM = g * RPW + (l & 15);

    // TAIL mapping (post-barrier)
    const int s    = l & 7;              // k-slice within tail group
    const int oi   = l >> 3;
    const int tq   = oi >> 1;            // gate for tail
    const int rh   = oi & 1;             // row sub 0/1
    const int rowT = g * RPW + 2 * w + rh;

    const float* Utab[4] = {Uf, Ui, Uo, Uc};
    const float* Wtab[4] = {Wf, Wi, Wo, Wc};
    const float* Btab[4] = {bf, bi, bo, bc};

    // load + pin weights: 64 U floats + 16 W floats per thread (main mapping)
    const float4* Up = (const float4*)(Utab[q] + (size_t)rowM * NHID + w * 64);
    #define DECLU(i) float4 u##i = Up[i];
    FOR16(DECLU)
    const float4* Wp = (const float4*)(Wtab[q] + rowM * NXW + w * 16);
    #define DECLW(i) float4 wv##i = Wp[i];
    FOR4(DECLW)
    #define PIN(r) asm volatile("" : "+v"(r.x), "+v"(r.y), "+v"(r.z), "+v"(r.w));
    #define PINU(i) PIN(u##i)
    FOR16(PINU)
    #define PINW(i) PIN(wv##i)
    FOR4(PINW)

    const float bias = Btab[tq][rowT];   // tail mapping
    float c_prev = 0.f;                  // c for rowT (replicated over tq,s)

    h_buf[w][l] = 0.f;                   // h[-1] = 0 (own wave reads only)

    for (int t = 0; t < STEPS; ++t) {
        if ((t & 127) == 0) {            // x window refill (covers x[t..t+255])
            __syncthreads();
            if (tid < 256) {
                int gi = t + tid;
                x_win[tid] = (gi < TLEN) ? x[gi] : 0.f;
            }
            __syncthreads();
        }

        // issue poll sample 0 before the x-projection (FMAs hide its latency)
        const unsigned want = (unsigned)(t - 1);
        const unsigned long long* src =
            ring + ((size_t)((t - 1) & (RSLOTS - 1)) << 9) + (w * 64 + l);
        unsigned long long vv = 0;
        if (t > 0) vv = AL(src);

        // x-projection partial (independent of h), 2 accumulators
        float xa0 = 0.f, xa1 = 0.f;
        {
            const int xb = (t & 127) + w * 16;
            #define XF(i, A) A += wv##i.x * x_win[xb + 4*i]     \
                                + wv##i.y * x_win[xb + 4*i + 1] \
                                + wv##i.z * x_win[xb + 4*i + 2] \
                                + wv##i.w * x_win[xb + 4*i + 3];
            XF(0, xa0) XF(1, xa1) XF(2, xa0) XF(3, xa1)
        }
        const float xacc = xa0 + xa1;

        // poll own 8B ring word of h[t-1]: R0-verbatim fabric
        if (t > 0) {
            int guard = 1 << 20;
            while ((unsigned)(vv >> 32) != want && --guard)
                vv = AL(src);
            h_buf[w][l] = __uint_as_float((unsigned)vv);
        }

        // U @ h slice: 64 FMA, 4 independent accumulators (R1-R3 verified)
        float ac0 = xacc, ac1 = 0.f, ac2 = 0.f, ac3 = 0.f;
        const float4* hb4 = (const float4*)h_buf[w];
        #define UF(i, A) { float4 hv = hb4[i];                    \
                           A += u##i.x * hv.x + u##i.y * hv.y     \
                              + u##i.z * hv.z + u##i.w * hv.w; }
        UF(0,  ac0) UF(1,  ac1) UF(2,  ac2) UF(3,  ac3)
        UF(4,  ac0) UF(5,  ac1) UF(6,  ac2) UF(7,  ac3)
        UF(8,  ac0) UF(9,  ac1) UF(10, ac2) UF(11, ac3)
        UF(12, ac0) UF(13, ac1) UF(14, ac2) UF(15, ac3)
        const float acc = (ac0 + ac1) + (ac2 + ac3);

        partials[t & 1][w * PSTRIDE + l] = acc;   // 2-way bank aliasing = free
        __syncthreads();                 // the ONE per-step barrier

        // ---- distributed tail: wave w finishes rows 2w, 2w+1 ----
        {
            const float* p = partials[t & 1];
            float pre = p[s * PSTRIDE + tq * 16 + 2 * w + rh];
            pre += __shfl_xor(pre, 1, 64);           // reduce over k-slices
            pre += __shfl_xor(pre, 2, 64);
            pre += __shfl_xor(pre, 4, 64);
            pre += bias;
            const float a = (tq < 3) ? sigmoid_f(pre) : tanh_f(pre);
            const int bl = l & 15;                   // (rh<<3)|s
            const float af = __shfl(a, bl,      64);
            const float ai = __shfl(a, bl + 16, 64);
            const float ao = __shfl(a, bl + 32, 64);
            const float ag = __shfl(a, bl + 48, 64);
            const float c  = af * c_prev + ai * ag;  // all lanes track c
            c_prev = c;
            const float h = ao * tanh_f(c);
            if (tq == 0 && s == 0) {                 // lanes 0,8: publish 2 rows
                unsigned long long pv =
                    ((unsigned long long)(unsigned)t << 32)
                    | (unsigned long long)__float_as_uint(h);
                ASTR(ring + ((size_t)(t & (RSLOTS - 1)) << 9) + rowT, pv);
                h_hist[(size_t)t * NHID + rowT] = h; // mu only, off-path
            }
        }
    }
}

// ---------------------------------------------------------------------------
// epilogue: mu[t] = Ahy . h_hist[t] + by   (one wave per t)
// ---------------------------------------------------------------------------
__global__ void mu_kernel(const float* __restrict__ h_hist,
                          const float* __restrict__ Ahy,
                          const float* __restrict__ by,
                          float* __restrict__ outp, int steps)
{
    int wave = threadIdx.x >> 6;
    int lane = threadIdx.x & 63;
    int t = blockIdx.x * 4 + wave;
    if (t >= steps) return;
    const float* h = h_hist + (size_t)t * NHID;
    float p = 0.f;
    #pragma unroll
    for (int e = 0; e < 8; e++)
        p += Ahy[e * 64 + lane] * h[e * 64 + lane];
    #pragma unroll
    for (int off = 32; off; off >>= 1) p += __shfl_down(p, off, 64);
    if (lane == 0) outp[t] = p + by[0];
}

// ---------------------------------------------------------------------------
extern "C" void kernel_launch(void* const* d_in, const int* in_sizes, int n_in,
                              void* d_out, int out_size, void* d_ws, size_t ws_size,
                              hipStream_t stream)
{
    const float* x  = (const float*)d_in[0];
    const float* Wf = (const float*)d_in[1];
    const float* Uf = (const float*)d_in[2];
    const float* bf = (const float*)d_in[3];
    const float* Wi = (const float*)d_in[4];
    const float* Ui = (const float*)d_in[5];
    const float* bi = (const float*)d_in[6];
    const float* Wo = (const float*)d_in[7];
    const float* Uo = (const float*)d_in[8];
    const float* bo = (const float*)d_in[9];
    const float* Wc = (const float*)d_in[10];
    const float* Uc = (const float*)d_in[11];
    const float* bc = (const float*)d_in[12];
    const float* Ahy = (const float*)d_in[13];
    const float* by  = (const float*)d_in[14];

    unsigned long long* ring = (unsigned long long*)d_ws;        // 32 KB
    float* h_hist = (float*)((char*)d_ws + RSLOTS * NHID * 8);   // ~33.3 MB

    lstm_persistent<<<G, B, 0, stream>>>(x, Wf, Uf, bf, Wi, Ui, bi,
                                         Wo, Uo, bo, Wc, Uc, bc, ring, h_hist);
    int muBlocks = (STEPS + 3) / 4;
    mu_kernel<<<muBlocks, 256, 0, stream>>>(h_hist, Ahy, by, (float*)d_out, STEPS);
}

// Round 9
// 30437.067 us; speedup vs baseline: 1.2066x; 1.2066x over previous
//
#include <hip/hip_runtime.h>

#define NHID 512
#define NXW  128
#define TLEN 16384
#define STEPS (TLEN - NXW)      // 16256
#define G    32                 // persistent workgroups
#define B    512                // 8 waves per WG
#define RPW  16                 // hidden rows owned per WG
#define RSLOTS 8                // sync ring depth (32 KB -> stays IC/L2-hot)

#define FOR4(M)  M(0) M(1) M(2) M(3)
#define FOR16(M) M(0) M(1) M(2) M(3) M(4) M(5) M(6) M(7) \
                 M(8) M(9) M(10) M(11) M(12) M(13) M(14) M(15)

__device__ __forceinline__ float sigmoid_f(float v) { return 1.f / (1.f + __expf(-v)); }
__device__ __forceinline__ float tanh_f(float v)    { return 1.f - 2.f / (1.f + __expf(2.f * v)); }

#define AL(p) __hip_atomic_load((p), __ATOMIC_RELAXED, __HIP_MEMORY_SCOPE_AGENT)
#define ASTR(p, v) __hip_atomic_store((p), (v), __ATOMIC_RELAXED, __HIP_MEMORY_SCOPE_AGENT)
#define LDS_REL(p, v) __hip_atomic_store((p), (v), __ATOMIC_RELEASE, __HIP_MEMORY_SCOPE_WORKGROUP)
#define LDS_ACQ(p)    __hip_atomic_load((p), __ATOMIC_ACQUIRE, __HIP_MEMORY_SCOPE_WORKGROUP)

// ---------------------------------------------------------------------------
// R9 = R0 skeleton (verified 25.6 ms) with the per-step __syncthreads
// replaced by per-wave LDS done-flags. Everything else is R0-verbatim
// (R8's lesson: wave0-does-tail / others-poll-early is the right division
// of labor; don't scatter the publish, don't put the tail on all waves).
//
// Flag protocol: wave w (w>=1) writes its partial slice, then RELEASE-stores
// pflag[w] = t (workgroup scope). Wave0 ACQUIRE-spins pflag[w] >= t and
// accumulates slices incrementally as they arrive, then activates/publishes
// exactly as R0. Waves 1-7 proceed straight to step t+1's poll — the
// barrier's arrive/release latency leaves wave0's serial chain.
//
// Overwrite safety (no barrier needed):
//  - partials[t&1] overwritten at step t+2: the writer validated ring tags
//    t+1; ANY tag t+1 requires every WG's 8 waves to have validated all 512
//    tags t (union of slices = all rows), i.e. every wave0 published t,
//    i.e. finished reading partials[t&1]. Safe.
//  - flag ABA (wave s writes pflag[s]=t+1 before wave0 consumed ==t):
//    impossible — s passes its step-t+1 poll only after its OWN wave0
//    published t, which required consuming pflag[s] >= t first.
//  - spin uses >= t (monotonic), guarded.
//
// Ring word = {tag:32 | h_bits:32}; consumer of step t polls slot (t-1)&7
// until tag == t-1. Harness 0xAA poison = tag 0xAAAAAAAA, never a valid t,
// so stale launches can't validate. Slot reuse is race-free: observing all
// tags t-1 proves every WG completed step t-1, i.e. finished reading every
// tag <= t-2, so overwriting slot t&7 (holding tag t-8) is safe.
// h_hist gets plain (non-sync) stores purely for the mu epilogue.
// x-window refill keeps its two barriers (2 per 128 steps, amortized ~0);
// skew across waves is bounded by the ring coupling to ~1 step, so all
// waves reach the refill point together.
// ---------------------------------------------------------------------------
__launch_bounds__(B, 2)
__global__ void lstm_persistent(
    const float* x,
    const float* Wf, const float* Uf, const float* bf,
    const float* Wi, const float* Ui, const float* bi,
    const float* Wo, const float* Uo, const float* bo,
    const float* Wc, const float* Uc, const float* bc,
    unsigned long long* ring,     // [RSLOTS][NHID] packed {tag,h}
    float* h_hist)                // [STEPS][NHID] for mu only
{
    __shared__ float x_win[256];                    // x ring: refill every 128 steps
    __shared__ __align__(16) float h_buf[8][64];    // per-wave h-slice staging
    __shared__ float partials[2][B];                // double-buffered
    __shared__ int pflag[8];                        // per-wave done flags

    const int tid = threadIdx.x;
    const int g   = blockIdx.x;
    const int w   = tid >> 6;            // wave = k-slice 0..7
    const int l   = tid & 63;            // output 0..63
    const int q   = l >> 4;              // gate 0=f 1=i 2=o 3=c
    const int row = g * RPW + (l & 15);

    const float* Utab[4] = {Uf, Ui, Uo, Uc};
    const float* Wtab[4] = {Wf, Wi, Wo, Wc};
    const float* Btab[4] = {bf, bi, bo, bc};

    // load + pin weights: 64 U floats + 16 W floats per thread (R0-proven)
    const float4* Up = (const float4*)(Utab[q] + (size_t)row * NHID + w * 64);
    #define DECLU(i) float4 u##i = Up[i];
    FOR16(DECLU)
    const float4* Wp = (const float4*)(Wtab[q] + row * NXW + w * 16);
    #define DECLW(i) float4 wv##i = Wp[i];
    FOR4(DECLW)
    #define PIN(r) asm volatile("" : "+v"(r.x), "+v"(r.y), "+v"(r.z), "+v"(r.w));
    #define PINU(i) PIN(u##i)
    FOR16(PINU)
    #define PINW(i) PIN(wv##i)
    FOR4(PINW)

    float bias = 0.f, c_prev = 0.f;
    if (w == 0) bias = Btab[q][row];

    h_buf[w][l] = 0.f;                   // h[-1] = 0 (own wave reads only)
    if (tid < 8) pflag[tid] = -1;        // flags: nothing produced yet
    __syncthreads();                     // prologue barrier (covers pflag init)

    for (int t = 0; t < STEPS; ++t) {
        if ((t & 127) == 0) {            // x window refill (covers x[t..t+255])
            __syncthreads();
            if (tid < 256) {
                int gi = t + tid;
                x_win[tid] = (gi < TLEN) ? x[gi] : 0.f;
            }
            __syncthreads();
        }

        // issue poll sample 0 before the x-projection (FMAs hide its latency)
        const unsigned want = (unsigned)(t - 1);
        const unsigned long long* src =
            ring + ((size_t)((t - 1) & (RSLOTS - 1)) << 9) + (w * 64 + l);
        unsigned long long vv = 0;
        if (t > 0) vv = AL(src);

        // x-projection partial (independent of h), 2 accumulators
        float xa0 = 0.f, xa1 = 0.f;
        {
            const int xb = (t & 127) + w * 16;
            #define XF(i, A) A += wv##i.x * x_win[xb + 4*i]     \
                                + wv##i.y * x_win[xb + 4*i + 1] \
                                + wv##i.z * x_win[xb + 4*i + 2] \
                                + wv##i.w * x_win[xb + 4*i + 3];
            XF(0, xa0) XF(1, xa1) XF(2, xa0) XF(3, xa1)
        }
        const float xacc = xa0 + xa1;

        // poll own 8B ring word of h[t-1]: R0-verbatim fabric
        if (t > 0) {
            int guard = 1 << 20;
            while ((unsigned)(vv >> 32) != want && --guard)
                vv = AL(src);
            h_buf[w][l] = __uint_as_float((unsigned)vv);
        }

        // U @ h slice: 64 FMA, 4 independent accumulators (R1-R3 verified)
        float ac0 = xacc, ac1 = 0.f, ac2 = 0.f, ac3 = 0.f;
        const float4* hb4 = (const float4*)h_buf[w];
        #define UF(i, A) { float4 hv = hb4[i];                    \
                           A += u##i.x * hv.x + u##i.y * hv.y     \
                              + u##i.z * hv.z + u##i.w * hv.w; }
        UF(0,  ac0) UF(1,  ac1) UF(2,  ac2) UF(3,  ac3)
        UF(4,  ac0) UF(5,  ac1) UF(6,  ac2) UF(7,  ac3)
        UF(8,  ac0) UF(9,  ac1) UF(10, ac2) UF(11, ac3)
        UF(12, ac0) UF(13, ac1) UF(14, ac2) UF(15, ac3)
        const float acc = (ac0 + ac1) + (ac2 + ac3);

        if (w != 0) {
            partials[t & 1][tid] = acc;
            LDS_REL(&pflag[w], t);       // partial ready; straight to next step
        } else {
            // wave-0 tail: accumulate slices as they arrive, activate, publish
            const float* p = partials[t & 1];
            float pre = acc + bias;
            #pragma unroll
            for (int s2 = 1; s2 < 8; ++s2) {
                int guard = 1 << 20;
                while (LDS_ACQ(&pflag[s2]) < t && --guard) {}
                pre += p[s2 * 64 + l];
            }
            float a = (l < 48) ? sigmoid_f(pre) : tanh_f(pre);   // f,i,o / g
            float ai = __shfl(a, l + 16, 64);
            float ao = __shfl(a, l + 32, 64);
            float ag = __shfl(a, l + 48, 64);
            if (l < 16) {
                float c = a * c_prev + ai * ag;
                c_prev = c;
                float h = ao * tanh_f(c);
                unsigned long long pv =
                    ((unsigned long long)(unsigned)t << 32)
                    | (unsigned long long)__float_as_uint(h);
                ASTR(ring + ((size_t)(t & (RSLOTS - 1)) << 9) + row, pv);
                h_hist[(size_t)t * NHID + row] = h;   // mu only, off-path
            }
        }
    }
}

// ---------------------------------------------------------------------------
// epilogue: mu[t] = Ahy . h_hist[t] + by   (one wave per t)
// ---------------------------------------------------------------------------
__global__ void mu_kernel(const float* __restrict__ h_hist,
                          const float* __restrict__ Ahy,
                          const float* __restrict__ by,
                          float* __restrict__ outp, int steps)
{
    int wave = threadIdx.x >> 6;
    int lane = threadIdx.x & 63;
    int t = blockIdx.x * 4 + wave;
    if (t >= steps) return;
    const float* h = h_hist + (size_t)t * NHID;
    float p = 0.f;
    #pragma unroll
    for (int e = 0; e < 8; e++)
        p += Ahy[e * 64 + lane] * h[e * 64 + lane];
    #pragma unroll
    for (int off = 32; off; off >>= 1) p += __shfl_down(p, off, 64);
    if (lane == 0) outp[t] = p + by[0];
}

// ---------------------------------------------------------------------------
extern "C" void kernel_launch(void* const* d_in, const int* in_sizes, int n_in,
                              void* d_out, int out_size, void* d_ws, size_t ws_size,
                              hipStream_t stream)
{
    const float* x  = (const float*)d_in[0];
    const float* Wf = (const float*)d_in[1];
    const float* Uf = (const float*)d_in[2];
    const float* bf = (const float*)d_in[3];
    const float* Wi = (const float*)d_in[4];
    const float* Ui = (const float*)d_in[5];
    const float* bi = (const float*)d_in[6];
    const float* Wo = (const float*)d_in[7];
    const float* Uo = (const float*)d_in[8];
    const float* bo = (const float*)d_in[9];
    const float* Wc = (const float*)d_in[10];
    const float* Uc = (const float*)d_in[11];
    const float* bc = (const float*)d_in[12];
    const float* Ahy = (const float*)d_in[13];
    const float* by  = (const float*)d_in[14];

    unsigned long long* ring = (unsigned long long*)d_ws;        // 32 KB
    float* h_hist = (float*)((char*)d_ws + RSLOTS * NHID * 8);   // ~33.3 MB

    lstm_persistent<<<G, B, 0, stream>>>(x, Wf, Uf, bf, Wi, Ui, bi,
                                         Wo, Uo, bo, Wc, Uc, bc, ring, h_hist);
    int muBlocks = (STEPS + 3) / 4;
    mu_kernel<<<muBlocks, 256, 0, stream>>>(h_hist, Ahy, by, (float*)d_out, STEPS);
}

// Round 10
// 25291.135 us; speedup vs baseline: 1.4521x; 1.2035x over previous
//
#include <hip/hip_runtime.h>

#define NHID 512
#define NXW  128
#define TLEN 16384
#define STEPS (TLEN - NXW)      // 16256
#define G    32                 // persistent workgroups
#define B    512                // 8 waves per WG
#define RPW  16                 // hidden rows owned per WG
#define RSLOTS 8                // sync ring depth (32 KB -> stays IC/L2-hot)

#define FOR4(M)  M(0) M(1) M(2) M(3)
#define FOR16(M) M(0) M(1) M(2) M(3) M(4) M(5) M(6) M(7) \
                 M(8) M(9) M(10) M(11) M(12) M(13) M(14) M(15)

__device__ __forceinline__ float tanh_f(float v) { return 1.f - 2.f / (1.f + __expf(2.f * v)); }

// ---------------------------------------------------------------------------
// R10 = R0 skeleton (verified 25.6 ms), restored verbatim after the R8/R9
// excursions, with ONE change: wave0's tail activation is branch-free.
//
// R0 computed (l<48) ? sigmoid(pre) : tanh(pre) — both transcendental chains
// execute serially under divergence on the tail's critical path. Unified:
//   sigmoid(v) = 0 + 1/(1+exp(-1*v))
//   tanh(v)    = 1 - 2/(1+exp( 2*v))
// i.e. a = A + B/(1+exp(k*v)) with per-lane constants (k,A,B) selected
// wave-uniformly (no branch): one exp + one divide for all 64 lanes.
//
// Everything else is R0-verbatim. Nine-round ledger that justifies freezing
// this structure: poll-side changes neutral (R2,R3); XCD-local sync
// failed/neutral (R1,R5,R6,R7 — R6 proved even L2-speed consumer polling
// with single-XCD placement doesn't move the period); tail distribution
// regressed 43% (R8); LDS-flag barrier replacement regressed 19% (R9).
// The step period is pinned by producer->IC visibility + full-fan-in
// combine (dense U needs ALL of h[t-1]) + serial tail + wave skew.
//
// Ring word = {tag:32 | h_bits:32}; consumer of step t polls slot (t-1)&7
// until tag == t-1. Harness 0xAA poison = tag 0xAAAAAAAA, never a valid t,
// so stale launches can't validate. Slot reuse is race-free: observing all
// tags t-1 proves every WG completed step t-1, i.e. finished reading every
// tag <= t-2, so overwriting slot t&7 (holding tag t-8) is safe.
// h_hist gets plain (non-sync) stores purely for the mu epilogue.
// ---------------------------------------------------------------------------
__launch_bounds__(B, 2)
__global__ void lstm_persistent(
    const float* x,
    const float* Wf, const float* Uf, const float* bf,
    const float* Wi, const float* Ui, const float* bi,
    const float* Wo, const float* Uo, const float* bo,
    const float* Wc, const float* Uc, const float* bc,
    unsigned long long* ring,     // [RSLOTS][NHID] packed {tag,h}
    float* h_hist)                // [STEPS][NHID] for mu only
{
    __shared__ float x_win[256];                    // x ring: refill every 128 steps
    __shared__ __align__(16) float h_buf[8][64];    // per-wave h-slice staging
    __shared__ float partials[2][B];                // double-buffered

    const int tid = threadIdx.x;
    const int g   = blockIdx.x;
    const int w   = tid >> 6;            // wave = k-slice 0..7
    const int l   = tid & 63;            // output 0..63
    const int q   = l >> 4;              // gate 0=f 1=i 2=o 3=c
    const int row = g * RPW + (l & 15);

    const float* Utab[4] = {Uf, Ui, Uo, Uc};
    const float* Wtab[4] = {Wf, Wi, Wo, Wc};
    const float* Btab[4] = {bf, bi, bo, bc};

    // load + pin weights: 64 U floats + 16 W floats per thread (R0-proven)
    const float4* Up = (const float4*)(Utab[q] + (size_t)row * NHID + w * 64);
    #define DECLU(i) float4 u##i = Up[i];
    FOR16(DECLU)
    const float4* Wp = (const float4*)(Wtab[q] + row * NXW + w * 16);
    #define DECLW(i) float4 wv##i = Wp[i];
    FOR4(DECLW)
    #define PIN(r) asm volatile("" : "+v"(r.x), "+v"(r.y), "+v"(r.z), "+v"(r.w));
    #define PINU(i) PIN(u##i)
    FOR16(PINU)
    #define PINW(i) PIN(wv##i)
    FOR4(PINW)

    float bias = 0.f, c_prev = 0.f;
    if (w == 0) bias = Btab[q][row];

    // branch-free activation constants for the tail (wave-uniform selects):
    // lanes l<48 (f,i,o): sigmoid -> k=-1, A=0, B=+1
    // lanes l>=48   (g) : tanh    -> k=+2, A=1, B=-2
    const float akc = (l < 48) ? -1.f : 2.f;
    const float aA  = (l < 48) ?  0.f : 1.f;
    const float aB  = (l < 48) ?  1.f : -2.f;

    h_buf[w][l] = 0.f;                   // h[-1] = 0 (own wave reads only)

    for (int t = 0; t < STEPS; ++t) {
        if ((t & 127) == 0) {            // x window refill (covers x[t..t+255])
            __syncthreads();
            if (tid < 256) {
                int gi = t + tid;
                x_win[tid] = (gi < TLEN) ? x[gi] : 0.f;
            }
            __syncthreads();
        }

        // x-projection partial (independent of h -> overlaps producer latency)
        float xacc = 0.f;
        {
            const int xb = (t & 127) + w * 16;
            #define XF(i) xacc += wv##i.x * x_win[xb + 4*i]     \
                                + wv##i.y * x_win[xb + 4*i + 1] \
                                + wv##i.z * x_win[xb + 4*i + 2] \
                                + wv##i.w * x_win[xb + 4*i + 3];
            FOR4(XF)
        }

        // poll own 8B ring word of h[t-1]: hot line, tag-validated
        if (t > 0) {
            const unsigned long long* src =
                ring + ((size_t)((t - 1) & (RSLOTS - 1)) << 9) + (w * 64 + l);
            const unsigned want = (unsigned)(t - 1);
            unsigned long long vv; int guard = 0;
            do {
                vv = __hip_atomic_load(src, __ATOMIC_RELAXED, __HIP_MEMORY_SCOPE_AGENT);
            } while ((unsigned)(vv >> 32) != want && ++guard < (1 << 20));
            h_buf[w][l] = __uint_as_float((unsigned)vv);
        }

        // U @ h slice: 64 FMA vs wave-uniform LDS broadcast reads
        float acc = xacc;
        const float4* hb4 = (const float4*)h_buf[w];
        #define UF(i) { float4 hv = hb4[i];                       \
                        acc += u##i.x * hv.x + u##i.y * hv.y      \
                             + u##i.z * hv.z + u##i.w * hv.w; }
        FOR16(UF)
        partials[t & 1][(w << 6) | l] = acc;
        __syncthreads();                 // the ONE per-step barrier

        // wave-0 tail: reduce 8 k-slices, activate, combine, publish to ring
        if (w == 0) {
            const float* p = partials[t & 1];
            float pre = acc + bias;
            #pragma unroll
            for (int s2 = 1; s2 < 8; ++s2) pre += p[s2 * 64 + l];
            // branch-free unified activation (one exp + one div for all lanes)
            float e = __expf(akc * pre);
            float a = aA + aB / (1.f + e);           // f,i,o: sigmoid / g: tanh
            float ai = __shfl(a, l + 16, 64);
            float ao = __shfl(a, l + 32, 64);
            float ag = __shfl(a, l + 48, 64);
            if (l < 16) {
                float c = a * c_prev + ai * ag;
                c_prev = c;
                float h = ao * tanh_f(c);
                unsigned long long pv =
                    ((unsigned long long)(unsigned)t << 32)
                    | (unsigned long long)__float_as_uint(h);
                __hip_atomic_store(
                    ring + ((size_t)(t & (RSLOTS - 1)) << 9) + row, pv,
                    __ATOMIC_RELAXED, __HIP_MEMORY_SCOPE_AGENT);
                h_hist[(size_t)t * NHID + row] = h;   // mu only, off-path
            }
        }
    }
}

// ---------------------------------------------------------------------------
// epilogue: mu[t] = Ahy . h_hist[t] + by   (one wave per t)
// ---------------------------------------------------------------------------
__global__ void mu_kernel(const float* __restrict__ h_hist,
                          const float* __restrict__ Ahy,
                          const float* __restrict__ by,
                          float* __restrict__ outp, int steps)
{
    int wave = threadIdx.x >> 6;
    int lane = threadIdx.x & 63;
    int t = blockIdx.x * 4 + wave;
    if (t >= steps) return;
    const float* h = h_hist + (size_t)t * NHID;
    float p = 0.f;
    #pragma unroll
    for (int e = 0; e < 8; e++)
        p += Ahy[e * 64 + lane] * h[e * 64 + lane];
    #pragma unroll
    for (int off = 32; off; off >>= 1) p += __shfl_down(p, off, 64);
    if (lane == 0) outp[t] = p + by[0];
}

// ---------------------------------------------------------------------------
extern "C" void kernel_launch(void* const* d_in, const int* in_sizes, int n_in,
                              void* d_out, int out_size, void* d_ws, size_t ws_size,
                              hipStream_t stream)
{
    const float* x  = (const float*)d_in[0];
    const float* Wf = (const float*)d_in[1];
    const float* Uf = (const float*)d_in[2];
    const float* bf = (const float*)d_in[3];
    const float* Wi = (const float*)d_in[4];
    const float* Ui = (const float*)d_in[5];
    const float* bi = (const float*)d_in[6];
    const float* Wo = (const float*)d_in[7];
    const float* Uo = (const float*)d_in[8];
    const float* bo = (const float*)d_in[9];
    const float* Wc = (const float*)d_in[10];
    const float* Uc = (const float*)d_in[11];
    const float* bc = (const float*)d_in[12];
    const float* Ahy = (const float*)d_in[13];
    const float* by  = (const float*)d_in[14];

    unsigned long long* ring = (unsigned long long*)d_ws;        // 32 KB
    float* h_hist = (float*)((char*)d_ws + RSLOTS * NHID * 8);   // ~33.3 MB

    lstm_persistent<<<G, B, 0, stream>>>(x, Wf, Uf, bf, Wi, Ui, bi,
                                         Wo, Uo, bo, Wc, Uc, bc, ring, h_hist);
    int muBlocks = (STEPS + 3) / 4;
    mu_kernel<<<muBlocks, 256, 0, stream>>>(h_hist, Ahy, by, (float*)d_out, STEPS);
}